// Round 11
// baseline (207.139 us; speedup 1.0000x reference)
//
#include <hip/hip_runtime.h>
#include <hip/hip_bf16.h>
#include <stdint.h>

#define T_TOK 4096
#define T1N   4097
#define DMODEL 512
#define VTS   4160   // padded column count of transposed V (65*64)
#define EMB_BLKS 1025   // ceil(4097/4)

typedef __attribute__((ext_vector_type(8))) short bf16x8;
typedef __attribute__((ext_vector_type(4))) float f32x4;

static __device__ __forceinline__ unsigned short f2bf(float f) {
  __hip_bfloat16 h = __float2bfloat16(f);
  return *reinterpret_cast<unsigned short*>(&h);
}
static __device__ __forceinline__ float bf2f(unsigned short u) {
  __hip_bfloat16 h = *reinterpret_cast<__hip_bfloat16*>(&u);
  return __bfloat162float(h);
}

// stage a ROWSx64 bf16 tile src[row0..row0+ROWS)[k0..k0+64) (row stride srcld) into LINEAR
// lds[ROWS][64] via global_load_lds width=16. LDS dest = wave-uniform base + lane*16B.
template<int ROWS>
static __device__ __forceinline__ void stage_rows(
    const __hip_bfloat16* __restrict__ src, __hip_bfloat16* lds,
    int row0, int k0, int srcld, int maxrow, int wave, int lane) {
  #pragma unroll
  for (int i = 0; i < ROWS/32; i++) {
    int row = wave*8 + i*32 + (lane>>3);
    int grow = row0 + row; if (grow > maxrow) grow = maxrow;
    const __hip_bfloat16* g = src + (size_t)grow*srcld + k0 + (lane&7)*8;
    __hip_bfloat16* l = lds + (wave*8 + i*32)*64;   // wave-uniform; HW adds lane*16B
    __builtin_amdgcn_global_load_lds(
        (const __attribute__((address_space(1))) void*)g,
        (__attribute__((address_space(3))) void*)l, 16, 0, 0);
  }
}

// ---------------- merged prep: embedding (wave-per-row) AND weight transpose+cast ----------------
__global__ __launch_bounds__(256) void prep_kernel(
    const int* __restrict__ aseq, const int* __restrict__ bid,
    const float* __restrict__ Wt, const float* __restrict__ bt,
    const float* __restrict__ Wa, const float* __restrict__ ba,
    const float* __restrict__ sosv,
    const float* __restrict__ Wq, const float* __restrict__ Wk,
    const float* __restrict__ Wv, const float* __restrict__ Wo,
    const float* __restrict__ W1, const float* __restrict__ W2,
    __hip_bfloat16* __restrict__ xb,
    int* __restrict__ ss, __hip_bfloat16* __restrict__ wtout) {
  __shared__ float tile[32][33];
  const int b = blockIdx.x;
  const int tid = threadIdx.x;
  if (b < EMB_BLKS) {
    const int wid = tid >> 6, lane = tid & 63;
    const int i = b*4 + wid;
    if (i >= T1N) return;       // wave-uniform, no barriers in this branch
    const int d0 = lane*8;
    float o[8];
    if (i == 0) {
      float4 s0 = *(const float4*)(sosv + d0);
      float4 s1 = *(const float4*)(sosv + d0 + 4);
      o[0]=s0.x; o[1]=s0.y; o[2]=s0.z; o[3]=s0.w;
      o[4]=s1.x; o[5]=s1.y; o[6]=s1.z; o[7]=s1.w;
    } else {
      int t = i - 1;
      int a0 = aseq[2*t], a1 = aseq[2*t+1];
      int key = bid[t];
      int lo = 0, hi = t;
      while (lo < hi) { int mid = (lo+hi) >> 1; if (bid[mid] < key) lo = mid + 1; else hi = mid; }
      if (lane == 0) ss[t] = lo;
      float pos = (float)(t - lo);
      const float* wt = Wt + (size_t)a0*DMODEL + d0;
      const float* wa = Wa + (size_t)(a1+1)*DMODEL + d0;
      float4 w0 = *(const float4*)wt,        w1 = *(const float4*)(wt+4);
      float4 a0v = *(const float4*)wa,       a1v = *(const float4*)(wa+4);
      float4 bt0 = *(const float4*)(bt+d0),  bt1 = *(const float4*)(bt+d0+4);
      float4 ba0 = *(const float4*)(ba+d0),  ba1 = *(const float4*)(ba+d0+4);
      float wsum[8] = {w0.x+a0v.x+bt0.x+ba0.x, w0.y+a0v.y+bt0.y+ba0.y,
                       w0.z+a0v.z+bt0.z+ba0.z, w0.w+a0v.w+bt0.w+ba0.w,
                       w1.x+a1v.x+bt1.x+ba1.x, w1.y+a1v.y+bt1.y+ba1.y,
                       w1.z+a1v.z+bt1.z+ba1.z, w1.w+a1v.w+bt1.w+ba1.w};
      #pragma unroll
      for (int j = 0; j < 8; j++) {
        int d = d0 + j;
        float dv = __expf(-9.210340371976184f * (float)(d & ~1) * (1.0f/(float)DMODEL));
        float ang = pos * dv;
        float pe = (d & 1) ? cosf(ang) : sinf(ang);
        o[j] = wsum[j] + pe;
      }
    }
    unsigned pk[4];
    #pragma unroll
    for (int j = 0; j < 4; j++)
      pk[j] = (unsigned)f2bf(o[2*j]) | ((unsigned)f2bf(o[2*j+1]) << 16);
    *(uint4*)(xb + (size_t)i*DMODEL + d0) = *(uint4*)pk;
  } else {
    int w = b - EMB_BLKS;
    int m = w >> 8;                 // 0..11 : kind*2 + layer
    int rem = w & 255;
    int bn = (rem >> 4) * 32;
    int bk = (rem & 15) * 32;
    int kind = m >> 1, layer = m & 1;
    const float* src = kind==0?Wq: kind==1?Wk: kind==2?Wv: kind==3?Wo: kind==4?W1:W2;
    src += (size_t)layer*DMODEL*DMODEL;
    __hip_bfloat16* dst = wtout + (size_t)m*DMODEL*DMODEL;
    int tx = tid & 31, ty = tid >> 5;
    for (int r = ty; r < 32; r += 8)
      tile[r][tx] = src[(size_t)(bk + r)*DMODEL + bn + tx];   // tile[kk][nn]
    __syncthreads();
    for (int r = ty; r < 32; r += 8)
      dst[(size_t)(bn + r)*DMODEL + bk + tx] = __float2bfloat16(tile[tx][r]); // dst[n][k]
  }
}

// ---------------- bf16 MFMA GEMM (proven): single-buffer gload_lds, 2 barriers/K-step ----------
template<int ACT>
__global__ __launch_bounds__(256) void gemm_one(
    const __hip_bfloat16* __restrict__ A, const __hip_bfloat16* __restrict__ Bt,
    const float* __restrict__ bias, __hip_bfloat16* __restrict__ Cb, int M) {
  constexpr int K = 512, N = 512;
  __shared__ __align__(16) __hip_bfloat16 As[64*64];
  __shared__ __align__(16) __hip_bfloat16 Bs[64*64];
  const int tid = threadIdx.x;
  const int m0 = blockIdx.x * 64;
  const int n0 = blockIdx.y * 64;
  const int lane = tid & 63, wave = tid >> 6;
  const int wm = wave >> 1, wn = wave & 1;
  f32x4 acc[2][2] = {};
  for (int k0 = 0; k0 < K; k0 += 64) {
    __syncthreads();   // prior reads of As/Bs done
    stage_rows<64>(A,  As, m0, k0, K, M-1, wave, lane);
    stage_rows<64>(Bt, Bs, n0, k0, K, N-1, wave, lane);
    __syncthreads();   // vmcnt(0) drained at barrier -> LDS writes landed
    #pragma unroll
    for (int kc = 0; kc < 64; kc += 32) {
      bf16x8 af[2], bf[2];
      #pragma unroll
      for (int i2 = 0; i2 < 2; i2++) {
        af[i2] = *(const bf16x8*)&As[(wm*32 + i2*16 + (lane&15))*64 + kc + (lane>>4)*8];
        bf[i2] = *(const bf16x8*)&Bs[(wn*32 + i2*16 + (lane&15))*64 + kc + (lane>>4)*8];
      }
      #pragma unroll
      for (int mi = 0; mi < 2; mi++)
        #pragma unroll
        for (int ni = 0; ni < 2; ni++)
          acc[mi][ni] = __builtin_amdgcn_mfma_f32_16x16x32_bf16(af[mi], bf[ni], acc[mi][ni], 0, 0, 0);
    }
  }
  #pragma unroll
  for (int mi = 0; mi < 2; mi++) {
    int rbase = m0 + wm*32 + mi*16 + ((lane>>4)<<2);
    #pragma unroll
    for (int ni = 0; ni < 2; ni++) {
      int col = n0 + wn*32 + ni*16 + (lane&15);
      float bb = bias[col];
      #pragma unroll
      for (int r = 0; r < 4; r++) {
        int row = rbase + r;
        if (row < M) {
          float val = acc[mi][ni][r] + bb;
          if (ACT == 1) val = fmaxf(val, 0.0f);
          Cb[(size_t)row*N + col] = __float2bfloat16(val);
        }
      }
    }
  }
}

// ---------------- fused LN + FF1 GEMM: C = relu(LN(x+y) @ W1 + b1); n0==0 blocks emit LN(x+y) ----
__global__ __launch_bounds__(256) void gemm_ff1(
    const __hip_bfloat16* __restrict__ xcar, const __hip_bfloat16* __restrict__ yres,
    const float* __restrict__ lng, const float* __restrict__ lnb,
    const __hip_bfloat16* __restrict__ Bt, const float* __restrict__ bias,
    __hip_bfloat16* __restrict__ f1out, __hip_bfloat16* __restrict__ xnew, int M) {
  constexpr int K = 512, N = 512;
  __shared__ __align__(16) __hip_bfloat16 As[64*64];
  __shared__ __align__(16) __hip_bfloat16 Bs[64*64];
  __shared__ float2 stats[64];                     // (-mean*rstd, rstd)
  __shared__ __align__(16) float gs[512], bs[512]; // ln gamma/beta
  const int tid = threadIdx.x;
  const int m0 = blockIdx.x * 64;
  const int n0 = blockIdx.y * 64;
  const int lane = tid & 63, wave = tid >> 6;
  const int wm = wave >> 1, wn = wave & 1;

  // preload gamma/beta (f32) to LDS
  {
    int i2 = tid * 2;
    *(float2*)&gs[i2] = *(const float2*)(lng + i2);
    *(float2*)&bs[i2] = *(const float2*)(lnb + i2);
  }
  // prepass: per-row LN stats; 4 lanes per row, shfl reduce (lanes same wave)
  {
    const int r = tid >> 2, c4 = tid & 3;
    int grow = m0 + r; if (grow > M-1) grow = M-1;
    const __hip_bfloat16* xp = xcar + (size_t)grow*K + c4*8;
    const __hip_bfloat16* yp = yres + (size_t)grow*K + c4*8;
    float s = 0.f, sq = 0.f;
    #pragma unroll
    for (int c = 0; c < 16; c++) {
      uint4 xw = *(const uint4*)(xp + c*32);
      uint4 yw = *(const uint4*)(yp + c*32);
      #pragma unroll
      for (int j = 0; j < 4; j++) {
        unsigned xx = ((const unsigned*)&xw)[j], yy = ((const unsigned*)&yw)[j];
        float a0 = bf2f((unsigned short)(xx & 0xffff)) + bf2f((unsigned short)(yy & 0xffff));
        float a1 = bf2f((unsigned short)(xx >> 16))    + bf2f((unsigned short)(yy >> 16));
        s += a0 + a1; sq += a0*a0 + a1*a1;
      }
    }
    s  += __shfl_xor(s, 1);  s  += __shfl_xor(s, 2);
    sq += __shfl_xor(sq, 1); sq += __shfl_xor(sq, 2);
    if (c4 == 0) {
      float mean = s * (1.0f/512.0f);
      float var  = sq * (1.0f/512.0f) - mean*mean;
      float rstd = rsqrtf(var + 1e-5f);
      stats[r] = make_float2(-mean*rstd, rstd);
    }
  }

  f32x4 acc[2][2] = {};
  const bool wrx = (n0 == 0);
  for (int k0 = 0; k0 < K; k0 += 64) {
    __syncthreads();   // stats/gs/bs visible (first iter); prior MFMA reads done (later iters)
    // A-staging: reg-staged with LN applied; LINEAR layout identical to gload_lds path
    #pragma unroll
    for (int i = 0; i < 2; i++) {
      int row = wave*8 + i*32 + (lane>>3);
      int grow = m0 + row; if (grow > M-1) grow = M-1;
      int kc = k0 + (lane&7)*8;
      uint4 xw = *(const uint4*)(xcar + (size_t)grow*K + kc);
      uint4 yw = *(const uint4*)(yres + (size_t)grow*K + kc);
      float2 st = stats[row];
      float4 g0 = *(const float4*)&gs[kc], g1 = *(const float4*)&gs[kc+4];
      float4 b0 = *(const float4*)&bs[kc], b1v = *(const float4*)&bs[kc+4];
      float G[8]  = {g0.x,g0.y,g0.z,g0.w,g1.x,g1.y,g1.z,g1.w};
      float Bb[8] = {b0.x,b0.y,b0.z,b0.w,b1v.x,b1v.y,b1v.z,b1v.w};
      unsigned pk[4];
      #pragma unroll
      for (int j = 0; j < 4; j++) {
        unsigned xx = ((const unsigned*)&xw)[j], yy = ((const unsigned*)&yw)[j];
        float a0 = bf2f((unsigned short)(xx & 0xffff)) + bf2f((unsigned short)(yy & 0xffff));
        float a1 = bf2f((unsigned short)(xx >> 16))    + bf2f((unsigned short)(yy >> 16));
        float o0 = (a0*st.y + st.x)*G[2*j]   + Bb[2*j];
        float o1 = (a1*st.y + st.x)*G[2*j+1] + Bb[2*j+1];
        pk[j] = (unsigned)f2bf(o0) | ((unsigned)f2bf(o1) << 16);
      }
      *(uint4*)&As[row*64 + (lane&7)*8] = *(uint4*)pk;
      if (wrx) *(uint4*)(xnew + (size_t)grow*K + kc) = *(uint4*)pk;  // identical-byte dup on clamp
    }
    stage_rows<64>(Bt, Bs, n0, k0, K, N-1, wave, lane);
    __syncthreads();   // drains lgkm (ds_write) + vmcnt (gload_lds)
    #pragma unroll
    for (int kc = 0; kc < 64; kc += 32) {
      bf16x8 af[2], bf[2];
      #pragma unroll
      for (int i2 = 0; i2 < 2; i2++) {
        af[i2] = *(const bf16x8*)&As[(wm*32 + i2*16 + (lane&15))*64 + kc + (lane>>4)*8];
        bf[i2] = *(const bf16x8*)&Bs[(wn*32 + i2*16 + (lane&15))*64 + kc + (lane>>4)*8];
      }
      #pragma unroll
      for (int mi = 0; mi < 2; mi++)
        #pragma unroll
        for (int ni = 0; ni < 2; ni++)
          acc[mi][ni] = __builtin_amdgcn_mfma_f32_16x16x32_bf16(af[mi], bf[ni], acc[mi][ni], 0, 0, 0);
    }
  }
  #pragma unroll
  for (int mi = 0; mi < 2; mi++) {
    int rbase = m0 + wm*32 + mi*16 + ((lane>>4)<<2);
    #pragma unroll
    for (int ni = 0; ni < 2; ni++) {
      int col = n0 + wn*32 + ni*16 + (lane&15);
      float bb = bias[col];
      #pragma unroll
      for (int r = 0; r < 4; r++) {
        int row = rbase + r;
        if (row < M) {
          float val = fmaxf(acc[mi][ni][r] + bb, 0.0f);
          f1out[(size_t)row*N + col] = __float2bfloat16(val);
        }
      }
    }
  }
}

// ---------------- fused QKV GEMM, 128x128 tile, 4x4 acc/wave (m93-class) ----------------
__global__ __launch_bounds__(256) void gemm_qkv(
    const __hip_bfloat16* __restrict__ A,
    const __hip_bfloat16* __restrict__ B0, const __hip_bfloat16* __restrict__ B1,
    const __hip_bfloat16* __restrict__ B2,
    const float* __restrict__ bias0, const float* __restrict__ bias1, const float* __restrict__ bias2,
    __hip_bfloat16* __restrict__ C0, __hip_bfloat16* __restrict__ C1, __hip_bfloat16* __restrict__ vt,
    int M) {
  constexpr int K = 512;
  __shared__ __align__(16) __hip_bfloat16 As[128*64];
  __shared__ __align__(16) __hip_bfloat16 Bs[128*64];
  const int tid = threadIdx.x;
  const int m0 = blockIdx.x * 128;
  const int z  = blockIdx.y >> 2;
  const int n0 = (blockIdx.y & 3) * 128;
  const __hip_bfloat16* Bt = (z==0) ? B0 : (z==1) ? B1 : B2;
  const int lane = tid & 63, wave = tid >> 6;
  const int wr = wave >> 1, wc = wave & 1;   // wave quadrant: rows wr*64, cols wc*64
  f32x4 acc[4][4] = {};
  for (int k0 = 0; k0 < K; k0 += 64) {
    __syncthreads();
    stage_rows<128>(A,  As, m0, k0, K, M-1, wave, lane);
    stage_rows<128>(Bt, Bs, n0, k0, K, 511, wave, lane);
    __syncthreads();
    #pragma unroll
    for (int kc = 0; kc < 64; kc += 32) {
      bf16x8 af[4], bf[4];
      #pragma unroll
      for (int i2 = 0; i2 < 4; i2++) {
        af[i2] = *(const bf16x8*)&As[(wr*64 + i2*16 + (lane&15))*64 + kc + (lane>>4)*8];
        bf[i2] = *(const bf16x8*)&Bs[(wc*64 + i2*16 + (lane&15))*64 + kc + (lane>>4)*8];
      }
      if (z == 2) {
        #pragma unroll
        for (int mi = 0; mi < 4; mi++)
          #pragma unroll
          for (int ni = 0; ni < 4; ni++)
            acc[mi][ni] = __builtin_amdgcn_mfma_f32_16x16x32_bf16(bf[ni], af[mi], acc[mi][ni], 0, 0, 0);
      } else {
        #pragma unroll
        for (int mi = 0; mi < 4; mi++)
          #pragma unroll
          for (int ni = 0; ni < 4; ni++)
            acc[mi][ni] = __builtin_amdgcn_mfma_f32_16x16x32_bf16(af[mi], bf[ni], acc[mi][ni], 0, 0, 0);
      }
    }
  }
  if (z < 2) {
    __hip_bfloat16* Cz = (z==0) ? C0 : C1;
    const float* bz = (z==0) ? bias0 : bias1;
    #pragma unroll
    for (int mi = 0; mi < 4; mi++) {
      int rbase = m0 + wr*64 + mi*16 + ((lane>>4)<<2);
      #pragma unroll
      for (int ni = 0; ni < 4; ni++) {
        int col = n0 + wc*64 + ni*16 + (lane&15);
        float bb = bz[col];
        #pragma unroll
        for (int r = 0; r < 4; r++) {
          int row = rbase + r;
          if (row < M) Cz[(size_t)row*DMODEL + col] = __float2bfloat16(acc[mi][ni][r] + bb);
        }
      }
    }
  } else {
    // D-register dim = first operand (bf -> n); lane&15 = m
    #pragma unroll
    for (int ni = 0; ni < 4; ni++) {
      int rnbase = n0 + wc*64 + ni*16 + ((lane>>4)<<2);
      #pragma unroll
      for (int mi = 0; mi < 4; mi++) {
        int colm = m0 + wr*64 + mi*16 + (lane&15);
        if (colm < M) {
          #pragma unroll
          for (int r = 0; r < 4; r++) {
            int rn = rnbase + r;
            vt[(size_t)rn*VTS + colm] = __float2bfloat16(acc[mi][ni][r] + bias2[rn]);
          }
        }
      }
    }
  }
}

// ---------------- MFMA block-sparse flash attention (R8-proven: 1 wave/block) ----------------
__global__ __launch_bounds__(64) void attn_kernel(
    const __hip_bfloat16* __restrict__ q,   // [T1N][512] bf16
    const __hip_bfloat16* __restrict__ k,   // [T1N][512] bf16
    const __hip_bfloat16* __restrict__ vt,  // [512][VTS] bf16
    const int* __restrict__ ss,
    __hip_bfloat16* __restrict__ out) {
  const int h  = blockIdx.y;
  const int q0 = blockIdx.x * 16;
  const int lane = threadIdx.x;
  const int g  = lane >> 4;      // 0..3
  const int qi = lane & 15;      // 0..15
  const int qrow = q0 + qi;      // softmax-role query of this lane

  int qld = (qrow < T1N) ? qrow : (T1N-1);
  const __hip_bfloat16* qp = q + (size_t)qld*DMODEL + h*64 + g*8;
  bf16x8 qlo = *(const bf16x8*)qp;
  bf16x8 qhi = *(const bf16x8*)(qp + 32);

  int jl;                       // first allowed non-SOS key for this query
  if (qrow >= T1N)      jl = 0x7fffffff;
  else if (qrow == 0)   jl = 1;
  else                  jl = ss[qrow-1] + 1;

  // ---- SOS init: every query attends key 0; m := s(sos), weight 1 ----
  const __hip_bfloat16* k0p = k + h*64 + g*8;
  float part = 0.0f;
  #pragma unroll
  for (int e = 0; e < 8; e++) {
    part += __bfloat162float(((const __hip_bfloat16*)&qlo)[e]) * __bfloat162float(k0p[e]);
    part += __bfloat162float(((const __hip_bfloat16*)&qhi)[e]) * __bfloat162float(k0p[e+32]);
  }
  part += __shfl_xor(part, 16);
  part += __shfl_xor(part, 32);
  float m = part * 0.125f;
  float lsum = 1.0f;
  f32x4 o[4];
  #pragma unroll
  for (int d = 0; d < 4; d++) {
    float v0 = __bfloat162float(vt[(size_t)(h*64 + d*16 + qi)*VTS]);
    o[d] = (f32x4){v0, v0, v0, v0};
  }

  const int mjl = (q0 == 0) ? 1 : (ss[q0-1] + 1);   // min jl over wave (ss monotone)
  const int kb_lo = mjl & ~31;
  const int jmax = (q0 + 15 < T1N - 1) ? (q0 + 15) : (T1N - 1);

  const int src0 = ((g & 1) << 5) + qi;   // P-redistribution source lanes
  const bool hiHalf = (g >= 2);

  // current-tile K/V registers (preloaded)
  bf16x8 cka0, cka1, ckb0, ckb1, cv0, cv1, cv2, cv3;
  {
    int kr0 = kb_lo + qi;       if (kr0 > T1N-1) kr0 = T1N-1;
    int kr1 = kb_lo + 16 + qi;  if (kr1 > T1N-1) kr1 = T1N-1;
    const __hip_bfloat16* kp0 = k + (size_t)kr0*DMODEL + h*64 + g*8;
    const __hip_bfloat16* kp1 = k + (size_t)kr1*DMODEL + h*64 + g*8;
    cka0 = *(const bf16x8*)kp0; cka1 = *(const bf16x8*)(kp0 + 32);
    ckb0 = *(const bf16x8*)kp1; ckb1 = *(const bf16x8*)(kp1 + 32);
    const __hip_bfloat16* vp = vt + (size_t)(h*64 + qi)*VTS + kb_lo + g*8;
    cv0 = *(const bf16x8*)vp;
    cv1 = *(const bf16x8*)(vp + (size_t)16*VTS);
    cv2 = *(const bf16x8*)(vp + (size_t)32*VTS);
    cv3 = *(const bf16x8*)(vp + (size_t)48*VTS);
  }

  for (int kbb = kb_lo; kbb <= jmax; kbb += 32) {
    // ---- issue next tile's loads (barrier-free kernel: latency hides under compute) ----
    int kn = (kbb + 32 <= jmax) ? (kbb + 32) : kbb;
    bf16x8 nka0, nka1, nkb0, nkb1, nv0, nv1, nv2, nv3;
    {
      int kr0 = kn + qi;       if (kr0 > T1N-1) kr0 = T1N-1;
      int kr1 = kn + 16 + qi;  if (kr1 > T1N-1) kr1 = T1N-1;
      const __hip_bfloat16* kp0 = k + (size_t)kr0*DMODEL + h*64 + g*8;
      const __hip_bfloat16* kp1 = k + (size_t)kr1*DMODEL + h*64 + g*8;
      nka0 = *(const bf16x8*)kp0; nka1 = *(const bf16x8*)(kp0 + 32);
      nkb0 = *(const bf16x8*)kp1; nkb1 = *(const bf16x8*)(kp1 + 32);
      const __hip_bfloat16* vp = vt + (size_t)(h*64 + qi)*VTS + kn + g*8;
      nv0 = *(const bf16x8*)vp;
      nv1 = *(const bf16x8*)(vp + (size_t)16*VTS);
      nv2 = *(const bf16x8*)(vp + (size_t)32*VTS);
      nv3 = *(const bf16x8*)(vp + (size_t)48*VTS);
    }

    // ---- S^T tiles with current K ----
    f32x4 sA = {0,0,0,0}, sB = {0,0,0,0};
    sA = __builtin_amdgcn_mfma_f32_16x16x32_bf16(cka0, qlo, sA, 0, 0, 0);
    sA = __builtin_amdgcn_mfma_f32_16x16x32_bf16(cka1, qhi, sA, 0, 0, 0);
    sB = __builtin_amdgcn_mfma_f32_16x16x32_bf16(ckb0, qlo, sB, 0, 0, 0);
    sB = __builtin_amdgcn_mfma_f32_16x16x32_bf16(ckb1, qhi, sB, 0, 0, 0);

    // mask + scale
    float s[8];
    const int kA = kbb + 4*g, kB = kA + 16;
    #pragma unroll
    for (int r = 0; r < 4; r++) {
      s[r]   = (kA + r >= jl && kA + r <= qrow) ? sA[r]*0.125f : -1e30f;
      s[4+r] = (kB + r >= jl && kB + r <= qrow) ? sB[r]*0.125f : -1e30f;
    }
    float mx = s[0];
    #pragma unroll
    for (int i = 1; i < 8; i++) mx = fmaxf(mx, s[i]);
    mx = fmaxf(mx, __shfl_xor(mx, 16));
    mx = fmaxf(mx, __shfl_xor(mx, 32));
    float mnew = fmaxf(m, mx);
    float corr = __expf(m - mnew);
    m = mnew;
    float p[8], psum = 0.0f;
    #pragma unroll
    for (int i = 0; i < 8; i++) { p[i] = __expf(s[i] - mnew); psum += p[i]; }
    psum += __shfl_xor(psum, 16);
    psum += __shfl_xor(psum, 32);
    lsum = lsum*corr + psum;

    // redistribute P to PV A-fragment layout: pa[e] = bf16(P[qi][8g+e])
    bf16x8 pa;
    #pragma unroll
    for (int r = 0; r < 4; r++) {
      unsigned w = (unsigned)f2bf(p[r]) | ((unsigned)f2bf(p[4+r]) << 16);
      unsigned v0 = (unsigned)__shfl((int)w, src0);
      unsigned v1 = (unsigned)__shfl((int)w, src0 + 16);
      pa[r]     = (short)(hiHalf ? (v0 >> 16) : (v0 & 0xffff));
      pa[4 + r] = (short)(hiHalf ? (v1 >> 16) : (v1 & 0xffff));
    }

    // rescale accumulator: acc row r of this lane is query 4g+r
    float cq0 = __shfl(corr, 4*g + 0);
    float cq1 = __shfl(corr, 4*g + 1);
    float cq2 = __shfl(corr, 4*g + 2);
    float cq3 = __shfl(corr, 4*g + 3);
    f32x4 cqv = (f32x4){cq0, cq1, cq2, cq3};
    #pragma unroll
    for (int d = 0; d < 4; d++) o[d] *= cqv;

    o[0] = __builtin_amdgcn_mfma_f32_16x16x32_bf16(pa, cv0, o[0], 0, 0, 0);
    o[1] = __builtin_amdgcn_mfma_f32_16x16x32_bf16(pa, cv1, o[1], 0, 0, 0);
    o[2] = __builtin_amdgcn_mfma_f32_16x16x32_bf16(pa, cv2, o[2], 0, 0, 0);
    o[3] = __builtin_amdgcn_mfma_f32_16x16x32_bf16(pa, cv3, o[3], 0, 0, 0);

    // rotate prefetched registers in
    cka0 = nka0; cka1 = nka1; ckb0 = nkb0; ckb1 = nkb1;
    cv0 = nv0; cv1 = nv1; cv2 = nv2; cv3 = nv3;
  }

  // epilogue: lane holds O[q0+4g+r][h*64 + d*16 + qi]
  float inv = 1.0f / lsum;
  float li0 = __shfl(inv, 4*g + 0);
  float li1 = __shfl(inv, 4*g + 1);
  float li2 = __shfl(inv, 4*g + 2);
  float li3 = __shfl(inv, 4*g + 3);
  f32x4 liv = (f32x4){li0, li1, li2, li3};
  #pragma unroll
  for (int r = 0; r < 4; r++) {
    int row = q0 + 4*g + r;
    if (row < T1N) {
      __hip_bfloat16* op = out + (size_t)row*DMODEL + h*64 + qi;
      #pragma unroll
      for (int d = 0; d < 4; d++) op[d*16] = __float2bfloat16(o[d][r] * liv[r]);
    }
  }
}

// ---------------- residual + LayerNorm: wave-per-row, no LDS, no barriers ----------------
__global__ __launch_bounds__(256) void ln_kernel(
    const __hip_bfloat16* __restrict__ xin, const __hip_bfloat16* __restrict__ yin,
    const float* __restrict__ g, const float* __restrict__ b,
    __hip_bfloat16* __restrict__ xbout, float* __restrict__ fout) {
  const int wid = threadIdx.x >> 6, lane = threadIdx.x & 63;
  const int row = blockIdx.x*4 + wid;
  if (row >= T1N) return;       // wave-uniform
  const size_t base = (size_t)row*DMODEL + lane*8;
  uint4 xw = *(const uint4*)(xin + base);
  uint4 yw = *(const uint4*)(yin + base);
  float v[8];
  float s = 0.0f, sq = 0.0f;
  #pragma unroll
  for (int j = 0; j < 4; j++) {
    unsigned xx = ((const unsigned*)&xw)[j], yy = ((const unsigned*)&yw)[j];
    float a0 = bf2f((unsigned short)(xx & 0xffff)) + bf2f((unsigned short)(yy & 0xffff));
    float a1 = bf2f((unsigned short)(xx >> 16))    + bf2f((unsigned short)(yy >> 16));
    v[2*j] = a0; v[2*j+1] = a1;
    s += a0 + a1; sq += a0*a0 + a1*a1;
  }
  #pragma unroll
  for (int off = 1; off < 64; off <<= 1) {
    s  += __shfl_xor(s, off);
    sq += __shfl_xor(sq, off);
  }
  float mean = s * (1.0f/512.0f);
  float var  = sq * (1.0f/512.0f) - mean*mean;
  float rstd = rsqrtf(var + 1e-5f);
  float4 g0 = *(const float4*)(g + lane*8), g1 = *(const float4*)(g + lane*8 + 4);
  float4 b0 = *(const float4*)(b + lane*8), b1 = *(const float4*)(b + lane*8 + 4);
  float gg[8] = {g0.x,g0.y,g0.z,g0.w,g1.x,g1.y,g1.z,g1.w};
  float bb[8] = {b0.x,b0.y,b0.z,b0.w,b1.x,b1.y,b1.z,b1.w};
  float o[8];
  #pragma unroll
  for (int j = 0; j < 8; j++) o[j] = (v[j] - mean)*rstd*gg[j] + bb[j];
  unsigned pk[4];
  #pragma unroll
  for (int j = 0; j < 4; j++)
    pk[j] = (unsigned)f2bf(o[2*j]) | ((unsigned)f2bf(o[2*j+1]) << 16);
  *(uint4*)(xbout + base) = *(uint4*)pk;
  if (fout) {
    *(float4*)(fout + base)     = make_float4(o[0], o[1], o[2], o[3]);
    *(float4*)(fout + base + 4) = make_float4(o[4], o[5], o[6], o[7]);
  }
}

extern "C" void kernel_launch(void* const* d_in, const int* in_sizes, int n_in,
                              void* d_out, int out_size, void* d_ws, size_t ws_size,
                              hipStream_t stream) {
  const int*   aseq   = (const int*)d_in[0];
  const int*   bid    = (const int*)d_in[1];
  const float* W_type = (const float*)d_in[2];
  const float* b_type = (const float*)d_in[3];
  const float* W_arg  = (const float*)d_in[4];
  const float* b_arg  = (const float*)d_in[5];
  const float* sosv   = (const float*)d_in[6];
  const float* Wq = (const float*)d_in[7];
  const float* bq = (const float*)d_in[8];
  const float* Wk = (const float*)d_in[9];
  const float* bk = (const float*)d_in[10];
  const float* Wv = (const float*)d_in[11];
  const float* bv = (const float*)d_in[12];
  const float* Wo = (const float*)d_in[13];
  const float* bo = (const float*)d_in[14];
  const float* ln1g = (const float*)d_in[15];
  const float* ln1b = (const float*)d_in[16];
  const float* W1 = (const float*)d_in[17];
  const float* b1 = (const float*)d_in[18];
  const float* W2 = (const float*)d_in[19];
  const float* b2 = (const float*)d_in[20];
  const float* ln2g = (const float*)d_in[21];
  const float* ln2b = (const float*)d_in[22];

  char* wsp = (char*)d_ws;
  size_t off = 0;
  auto alloc = [&](size_t bytes) -> void* {
    void* p = wsp + off; off += (bytes + 255) & ~(size_t)255; return p;
  };
  __hip_bfloat16* WT  = (__hip_bfloat16*)alloc((size_t)12*512*512*2);
  __hip_bfloat16* xb  = (__hip_bfloat16*)alloc((size_t)T1N*DMODEL*2);
  __hip_bfloat16* xb2 = (__hip_bfloat16*)alloc((size_t)T1N*DMODEL*2);
  __hip_bfloat16* qb  = (__hip_bfloat16*)alloc((size_t)T1N*DMODEL*2);
  __hip_bfloat16* kbf = (__hip_bfloat16*)alloc((size_t)T1N*DMODEL*2);
  __hip_bfloat16* vtb = (__hip_bfloat16*)alloc((size_t)512*VTS*2);
  __hip_bfloat16* yb  = (__hip_bfloat16*)alloc((size_t)T1N*DMODEL*2);
  __hip_bfloat16* ab  = (__hip_bfloat16*)alloc((size_t)T1N*DMODEL*2);
  __hip_bfloat16* f1b = (__hip_bfloat16*)alloc((size_t)T1N*DMODEL*2);
  int* ss             = (int*)alloc((size_t)T_TOK*4);

  prep_kernel<<<dim3(EMB_BLKS + 12*256), 256, 0, stream>>>(
      aseq, bid, W_type, b_type, W_arg, b_arg, sosv,
      Wq, Wk, Wv, Wo, W1, W2, xb, ss, WT);

  const size_t WSZ = (size_t)512*512;
  const dim3 ggrid(65, 8);
  const dim3 qgrid(33, 12);
  for (int l = 0; l < 2; l++) {
    const __hip_bfloat16* Bq  = WT + (size_t)(0*2+l)*WSZ;
    const __hip_bfloat16* Bk  = WT + (size_t)(1*2+l)*WSZ;
    const __hip_bfloat16* Bv  = WT + (size_t)(2*2+l)*WSZ;
    const __hip_bfloat16* Bo  = WT + (size_t)(3*2+l)*WSZ;
    const __hip_bfloat16* Bf1 = WT + (size_t)(4*2+l)*WSZ;
    const __hip_bfloat16* Bf2 = WT + (size_t)(5*2+l)*WSZ;

    gemm_qkv<<<qgrid, 256, 0, stream>>>(xb, Bq, Bk, Bv,
        bq + l*512, bk + l*512, bv + l*512, qb, kbf, vtb, T1N);
    attn_kernel<<<dim3(257,8), 64, 0, stream>>>(qb, kbf, vtb, ss, ab);
    gemm_one<0><<<ggrid, 256, 0, stream>>>(ab, Bo, bo + l*512, yb, T1N);
    // fused: xb2 = LN1(xb + yb); f1b = relu(xb2 @ W1 + b1)
    gemm_ff1<<<ggrid, 256, 0, stream>>>(xb, yb, ln1g + l*512, ln1b + l*512,
                                        Bf1, b1 + l*512, f1b, xb2, T1N);
    gemm_one<0><<<ggrid, 256, 0, stream>>>(f1b, Bf2, b2 + l*512, yb, T1N);
    float* fout = (l == 1) ? (float*)d_out : nullptr;
    ln_kernel<<<dim3(1025), 256, 0, stream>>>(xb2, yb, ln2g + l*512, ln2b + l*512, xb, fout);
  }
}

// Round 12
// 176.383 us; speedup vs baseline: 1.1744x; 1.1744x over previous
//
#include <hip/hip_runtime.h>
#include <hip/hip_bf16.h>
#include <stdint.h>

#define T_TOK 4096
#define T1N   4097
#define DMODEL 512
#define VTS   4160   // padded column count of transposed V (65*64)
#define EMB_BLKS 1025   // ceil(4097/4)

typedef __attribute__((ext_vector_type(8))) short bf16x8;
typedef __attribute__((ext_vector_type(4))) float f32x4;

static __device__ __forceinline__ unsigned short f2bf(float f) {
  __hip_bfloat16 h = __float2bfloat16(f);
  return *reinterpret_cast<unsigned short*>(&h);
}
static __device__ __forceinline__ float bf2f(unsigned short u) {
  __hip_bfloat16 h = *reinterpret_cast<__hip_bfloat16*>(&u);
  return __bfloat162float(h);
}

// stage a ROWSx64 bf16 tile src[row0..row0+ROWS)[k0..k0+64) (row stride srcld) into LINEAR
// lds[ROWS][64] via global_load_lds width=16. LDS dest = wave-uniform base + lane*16B.
template<int ROWS>
static __device__ __forceinline__ void stage_rows(
    const __hip_bfloat16* __restrict__ src, __hip_bfloat16* lds,
    int row0, int k0, int srcld, int maxrow, int wave, int lane) {
  #pragma unroll
  for (int i = 0; i < ROWS/32; i++) {
    int row = wave*8 + i*32 + (lane>>3);
    int grow = row0 + row; if (grow > maxrow) grow = maxrow;
    const __hip_bfloat16* g = src + (size_t)grow*srcld + k0 + (lane&7)*8;
    __hip_bfloat16* l = lds + (wave*8 + i*32)*64;   // wave-uniform; HW adds lane*16B
    __builtin_amdgcn_global_load_lds(
        (const __attribute__((address_space(1))) void*)g,
        (__attribute__((address_space(3))) void*)l, 16, 0, 0);
  }
}

// ---------------- merged prep: embedding (wave-per-row) AND weight transpose+cast ----------------
__global__ __launch_bounds__(256) void prep_kernel(
    const int* __restrict__ aseq, const int* __restrict__ bid,
    const float* __restrict__ Wt, const float* __restrict__ bt,
    const float* __restrict__ Wa, const float* __restrict__ ba,
    const float* __restrict__ sosv,
    const float* __restrict__ Wq, const float* __restrict__ Wk,
    const float* __restrict__ Wv, const float* __restrict__ Wo,
    const float* __restrict__ W1, const float* __restrict__ W2,
    __hip_bfloat16* __restrict__ xb,
    int* __restrict__ ss, __hip_bfloat16* __restrict__ wtout) {
  __shared__ float tile[32][33];
  const int b = blockIdx.x;
  const int tid = threadIdx.x;
  if (b < EMB_BLKS) {
    const int wid = tid >> 6, lane = tid & 63;
    const int i = b*4 + wid;
    if (i >= T1N) return;       // wave-uniform, no barriers in this branch
    const int d0 = lane*8;
    float o[8];
    if (i == 0) {
      float4 s0 = *(const float4*)(sosv + d0);
      float4 s1 = *(const float4*)(sosv + d0 + 4);
      o[0]=s0.x; o[1]=s0.y; o[2]=s0.z; o[3]=s0.w;
      o[4]=s1.x; o[5]=s1.y; o[6]=s1.z; o[7]=s1.w;
    } else {
      int t = i - 1;
      int a0 = aseq[2*t], a1 = aseq[2*t+1];
      int key = bid[t];
      int lo = 0, hi = t;
      while (lo < hi) { int mid = (lo+hi) >> 1; if (bid[mid] < key) lo = mid + 1; else hi = mid; }
      if (lane == 0) ss[t] = lo;
      float pos = (float)(t - lo);
      const float* wt = Wt + (size_t)a0*DMODEL + d0;
      const float* wa = Wa + (size_t)(a1+1)*DMODEL + d0;
      float4 w0 = *(const float4*)wt,        w1 = *(const float4*)(wt+4);
      float4 a0v = *(const float4*)wa,       a1v = *(const float4*)(wa+4);
      float4 bt0 = *(const float4*)(bt+d0),  bt1 = *(const float4*)(bt+d0+4);
      float4 ba0 = *(const float4*)(ba+d0),  ba1 = *(const float4*)(ba+d0+4);
      float wsum[8] = {w0.x+a0v.x+bt0.x+ba0.x, w0.y+a0v.y+bt0.y+ba0.y,
                       w0.z+a0v.z+bt0.z+ba0.z, w0.w+a0v.w+bt0.w+ba0.w,
                       w1.x+a1v.x+bt1.x+ba1.x, w1.y+a1v.y+bt1.y+ba1.y,
                       w1.z+a1v.z+bt1.z+ba1.z, w1.w+a1v.w+bt1.w+ba1.w};
      #pragma unroll
      for (int j = 0; j < 8; j++) {
        int d = d0 + j;
        float dv = __expf(-9.210340371976184f * (float)(d & ~1) * (1.0f/(float)DMODEL));
        float ang = pos * dv;
        float pe = (d & 1) ? cosf(ang) : sinf(ang);
        o[j] = wsum[j] + pe;
      }
    }
    unsigned pk[4];
    #pragma unroll
    for (int j = 0; j < 4; j++)
      pk[j] = (unsigned)f2bf(o[2*j]) | ((unsigned)f2bf(o[2*j+1]) << 16);
    *(uint4*)(xb + (size_t)i*DMODEL + d0) = *(uint4*)pk;
  } else {
    int w = b - EMB_BLKS;
    int m = w >> 8;                 // 0..11 : kind*2 + layer
    int rem = w & 255;
    int bn = (rem >> 4) * 32;
    int bk = (rem & 15) * 32;
    int kind = m >> 1, layer = m & 1;
    const float* src = kind==0?Wq: kind==1?Wk: kind==2?Wv: kind==3?Wo: kind==4?W1:W2;
    src += (size_t)layer*DMODEL*DMODEL;
    __hip_bfloat16* dst = wtout + (size_t)m*DMODEL*DMODEL;
    int tx = tid & 31, ty = tid >> 5;
    for (int r = ty; r < 32; r += 8)
      tile[r][tx] = src[(size_t)(bk + r)*DMODEL + bn + tx];   // tile[kk][nn]
    __syncthreads();
    for (int r = ty; r < 32; r += 8)
      dst[(size_t)(bn + r)*DMODEL + bk + tx] = __float2bfloat16(tile[tx][r]); // dst[n][k]
  }
}

// ---------------- bf16 MFMA GEMM (proven): single-buffer gload_lds, 2 barriers/K-step ----------
template<int ACT>
__global__ __launch_bounds__(256) void gemm_one(
    const __hip_bfloat16* __restrict__ A, const __hip_bfloat16* __restrict__ Bt,
    const float* __restrict__ bias, __hip_bfloat16* __restrict__ Cb, int M) {
  constexpr int K = 512, N = 512;
  __shared__ __align__(16) __hip_bfloat16 As[64*64];
  __shared__ __align__(16) __hip_bfloat16 Bs[64*64];
  const int tid = threadIdx.x;
  const int m0 = blockIdx.x * 64;
  const int n0 = blockIdx.y * 64;
  const int lane = tid & 63, wave = tid >> 6;
  const int wm = wave >> 1, wn = wave & 1;
  f32x4 acc[2][2] = {};
  for (int k0 = 0; k0 < K; k0 += 64) {
    __syncthreads();   // prior reads of As/Bs done
    stage_rows<64>(A,  As, m0, k0, K, M-1, wave, lane);
    stage_rows<64>(Bt, Bs, n0, k0, K, N-1, wave, lane);
    __syncthreads();   // vmcnt(0) drained at barrier -> LDS writes landed
    #pragma unroll
    for (int kc = 0; kc < 64; kc += 32) {
      bf16x8 af[2], bf[2];
      #pragma unroll
      for (int i2 = 0; i2 < 2; i2++) {
        af[i2] = *(const bf16x8*)&As[(wm*32 + i2*16 + (lane&15))*64 + kc + (lane>>4)*8];
        bf[i2] = *(const bf16x8*)&Bs[(wn*32 + i2*16 + (lane&15))*64 + kc + (lane>>4)*8];
      }
      #pragma unroll
      for (int mi = 0; mi < 2; mi++)
        #pragma unroll
        for (int ni = 0; ni < 2; ni++)
          acc[mi][ni] = __builtin_amdgcn_mfma_f32_16x16x32_bf16(af[mi], bf[ni], acc[mi][ni], 0, 0, 0);
    }
  }
  #pragma unroll
  for (int mi = 0; mi < 2; mi++) {
    int rbase = m0 + wm*32 + mi*16 + ((lane>>4)<<2);
    #pragma unroll
    for (int ni = 0; ni < 2; ni++) {
      int col = n0 + wn*32 + ni*16 + (lane&15);
      float bb = bias[col];
      #pragma unroll
      for (int r = 0; r < 4; r++) {
        int row = rbase + r;
        if (row < M) {
          float val = acc[mi][ni][r] + bb;
          if (ACT == 1) val = fmaxf(val, 0.0f);
          Cb[(size_t)row*N + col] = __float2bfloat16(val);
        }
      }
    }
  }
}

// ---------------- fused QKV GEMM, 128x128 tile, 4x4 acc/wave (m93-class) ----------------
// grid (33, 12): z = blockIdx.y>>2 picks Q/K/V weight; n0 = (blockIdx.y&3)*128 within it.
// z<2: normal C[row][col]; z=2: swapped MFMA -> V^T written to vt[n][m].
__global__ __launch_bounds__(256) void gemm_qkv(
    const __hip_bfloat16* __restrict__ A,
    const __hip_bfloat16* __restrict__ B0, const __hip_bfloat16* __restrict__ B1,
    const __hip_bfloat16* __restrict__ B2,
    const float* __restrict__ bias0, const float* __restrict__ bias1, const float* __restrict__ bias2,
    __hip_bfloat16* __restrict__ C0, __hip_bfloat16* __restrict__ C1, __hip_bfloat16* __restrict__ vt,
    int M) {
  constexpr int K = 512;
  __shared__ __align__(16) __hip_bfloat16 As[128*64];
  __shared__ __align__(16) __hip_bfloat16 Bs[128*64];
  const int tid = threadIdx.x;
  const int m0 = blockIdx.x * 128;
  const int z  = blockIdx.y >> 2;
  const int n0 = (blockIdx.y & 3) * 128;
  const __hip_bfloat16* Bt = (z==0) ? B0 : (z==1) ? B1 : B2;
  const int lane = tid & 63, wave = tid >> 6;
  const int wr = wave >> 1, wc = wave & 1;   // wave quadrant: rows wr*64, cols wc*64
  f32x4 acc[4][4] = {};
  for (int k0 = 0; k0 < K; k0 += 64) {
    __syncthreads();
    stage_rows<128>(A,  As, m0, k0, K, M-1, wave, lane);
    stage_rows<128>(Bt, Bs, n0, k0, K, 511, wave, lane);
    __syncthreads();
    #pragma unroll
    for (int kc = 0; kc < 64; kc += 32) {
      bf16x8 af[4], bf[4];
      #pragma unroll
      for (int i2 = 0; i2 < 4; i2++) {
        af[i2] = *(const bf16x8*)&As[(wr*64 + i2*16 + (lane&15))*64 + kc + (lane>>4)*8];
        bf[i2] = *(const bf16x8*)&Bs[(wc*64 + i2*16 + (lane&15))*64 + kc + (lane>>4)*8];
      }
      if (z == 2) {
        #pragma unroll
        for (int mi = 0; mi < 4; mi++)
          #pragma unroll
          for (int ni = 0; ni < 4; ni++)
            acc[mi][ni] = __builtin_amdgcn_mfma_f32_16x16x32_bf16(bf[ni], af[mi], acc[mi][ni], 0, 0, 0);
      } else {
        #pragma unroll
        for (int mi = 0; mi < 4; mi++)
          #pragma unroll
          for (int ni = 0; ni < 4; ni++)
            acc[mi][ni] = __builtin_amdgcn_mfma_f32_16x16x32_bf16(af[mi], bf[ni], acc[mi][ni], 0, 0, 0);
      }
    }
  }
  if (z < 2) {
    __hip_bfloat16* Cz = (z==0) ? C0 : C1;
    const float* bz = (z==0) ? bias0 : bias1;
    #pragma unroll
    for (int mi = 0; mi < 4; mi++) {
      int rbase = m0 + wr*64 + mi*16 + ((lane>>4)<<2);
      #pragma unroll
      for (int ni = 0; ni < 4; ni++) {
        int col = n0 + wc*64 + ni*16 + (lane&15);
        float bb = bz[col];
        #pragma unroll
        for (int r = 0; r < 4; r++) {
          int row = rbase + r;
          if (row < M) Cz[(size_t)row*DMODEL + col] = __float2bfloat16(acc[mi][ni][r] + bb);
        }
      }
    }
  } else {
    // D-register dim = first operand (bf -> n); lane&15 = m
    #pragma unroll
    for (int ni = 0; ni < 4; ni++) {
      int rnbase = n0 + wc*64 + ni*16 + ((lane>>4)<<2);
      #pragma unroll
      for (int mi = 0; mi < 4; mi++) {
        int colm = m0 + wr*64 + mi*16 + (lane&15);
        if (colm < M) {
          #pragma unroll
          for (int r = 0; r < 4; r++) {
            int rn = rnbase + r;
            vt[(size_t)rn*VTS + colm] = __float2bfloat16(acc[mi][ni][r] + bias2[rn]);
          }
        }
      }
    }
  }
}

// ---------------- MFMA block-sparse flash attention (R8-proven: 1 wave/block) ----------------
__global__ __launch_bounds__(64) void attn_kernel(
    const __hip_bfloat16* __restrict__ q,   // [T1N][512] bf16
    const __hip_bfloat16* __restrict__ k,   // [T1N][512] bf16
    const __hip_bfloat16* __restrict__ vt,  // [512][VTS] bf16
    const int* __restrict__ ss,
    __hip_bfloat16* __restrict__ out) {
  const int h  = blockIdx.y;
  const int q0 = blockIdx.x * 16;
  const int lane = threadIdx.x;
  const int g  = lane >> 4;      // 0..3
  const int qi = lane & 15;      // 0..15
  const int qrow = q0 + qi;      // softmax-role query of this lane

  int qld = (qrow < T1N) ? qrow : (T1N-1);
  const __hip_bfloat16* qp = q + (size_t)qld*DMODEL + h*64 + g*8;
  bf16x8 qlo = *(const bf16x8*)qp;
  bf16x8 qhi = *(const bf16x8*)(qp + 32);

  int jl;                       // first allowed non-SOS key for this query
  if (qrow >= T1N)      jl = 0x7fffffff;
  else if (qrow == 0)   jl = 1;
  else                  jl = ss[qrow-1] + 1;

  // ---- SOS init: every query attends key 0; m := s(sos), weight 1 ----
  const __hip_bfloat16* k0p = k + h*64 + g*8;
  float part = 0.0f;
  #pragma unroll
  for (int e = 0; e < 8; e++) {
    part += __bfloat162float(((const __hip_bfloat16*)&qlo)[e]) * __bfloat162float(k0p[e]);
    part += __bfloat162float(((const __hip_bfloat16*)&qhi)[e]) * __bfloat162float(k0p[e+32]);
  }
  part += __shfl_xor(part, 16);
  part += __shfl_xor(part, 32);
  float m = part * 0.125f;
  float lsum = 1.0f;
  f32x4 o[4];
  #pragma unroll
  for (int d = 0; d < 4; d++) {
    float v0 = __bfloat162float(vt[(size_t)(h*64 + d*16 + qi)*VTS]);
    o[d] = (f32x4){v0, v0, v0, v0};
  }

  const int mjl = (q0 == 0) ? 1 : (ss[q0-1] + 1);   // min jl over wave (ss monotone)
  const int kb_lo = mjl & ~31;
  const int jmax = (q0 + 15 < T1N - 1) ? (q0 + 15) : (T1N - 1);

  const int src0 = ((g & 1) << 5) + qi;   // P-redistribution source lanes
  const bool hiHalf = (g >= 2);

  // current-tile K/V registers (preloaded)
  bf16x8 cka0, cka1, ckb0, ckb1, cv0, cv1, cv2, cv3;
  {
    int kr0 = kb_lo + qi;       if (kr0 > T1N-1) kr0 = T1N-1;
    int kr1 = kb_lo + 16 + qi;  if (kr1 > T1N-1) kr1 = T1N-1;
    const __hip_bfloat16* kp0 = k + (size_t)kr0*DMODEL + h*64 + g*8;
    const __hip_bfloat16* kp1 = k + (size_t)kr1*DMODEL + h*64 + g*8;
    cka0 = *(const bf16x8*)kp0; cka1 = *(const bf16x8*)(kp0 + 32);
    ckb0 = *(const bf16x8*)kp1; ckb1 = *(const bf16x8*)(kp1 + 32);
    const __hip_bfloat16* vp = vt + (size_t)(h*64 + qi)*VTS + kb_lo + g*8;
    cv0 = *(const bf16x8*)vp;
    cv1 = *(const bf16x8*)(vp + (size_t)16*VTS);
    cv2 = *(const bf16x8*)(vp + (size_t)32*VTS);
    cv3 = *(const bf16x8*)(vp + (size_t)48*VTS);
  }

  for (int kbb = kb_lo; kbb <= jmax; kbb += 32) {
    // ---- issue next tile's loads (barrier-free kernel: latency hides under compute) ----
    int kn = (kbb + 32 <= jmax) ? (kbb + 32) : kbb;
    bf16x8 nka0, nka1, nkb0, nkb1, nv0, nv1, nv2, nv3;
    {
      int kr0 = kn + qi;       if (kr0 > T1N-1) kr0 = T1N-1;
      int kr1 = kn + 16 + qi;  if (kr1 > T1N-1) kr1 = T1N-1;
      const __hip_bfloat16* kp0 = k + (size_t)kr0*DMODEL + h*64 + g*8;
      const __hip_bfloat16* kp1 = k + (size_t)kr1*DMODEL + h*64 + g*8;
      nka0 = *(const bf16x8*)kp0; nka1 = *(const bf16x8*)(kp0 + 32);
      nkb0 = *(const bf16x8*)kp1; nkb1 = *(const bf16x8*)(kp1 + 32);
      const __hip_bfloat16* vp = vt + (size_t)(h*64 + qi)*VTS + kn + g*8;
      nv0 = *(const bf16x8*)vp;
      nv1 = *(const bf16x8*)(vp + (size_t)16*VTS);
      nv2 = *(const bf16x8*)(vp + (size_t)32*VTS);
      nv3 = *(const bf16x8*)(vp + (size_t)48*VTS);
    }

    // ---- S^T tiles with current K ----
    f32x4 sA = {0,0,0,0}, sB = {0,0,0,0};
    sA = __builtin_amdgcn_mfma_f32_16x16x32_bf16(cka0, qlo, sA, 0, 0, 0);
    sA = __builtin_amdgcn_mfma_f32_16x16x32_bf16(cka1, qhi, sA, 0, 0, 0);
    sB = __builtin_amdgcn_mfma_f32_16x16x32_bf16(ckb0, qlo, sB, 0, 0, 0);
    sB = __builtin_amdgcn_mfma_f32_16x16x32_bf16(ckb1, qhi, sB, 0, 0, 0);

    // mask + scale
    float s[8];
    const int kA = kbb + 4*g, kB = kA + 16;
    #pragma unroll
    for (int r = 0; r < 4; r++) {
      s[r]   = (kA + r >= jl && kA + r <= qrow) ? sA[r]*0.125f : -1e30f;
      s[4+r] = (kB + r >= jl && kB + r <= qrow) ? sB[r]*0.125f : -1e30f;
    }
    float mx = s[0];
    #pragma unroll
    for (int i = 1; i < 8; i++) mx = fmaxf(mx, s[i]);
    mx = fmaxf(mx, __shfl_xor(mx, 16));
    mx = fmaxf(mx, __shfl_xor(mx, 32));
    float mnew = fmaxf(m, mx);
    float corr = __expf(m - mnew);
    m = mnew;
    float p[8], psum = 0.0f;
    #pragma unroll
    for (int i = 0; i < 8; i++) { p[i] = __expf(s[i] - mnew); psum += p[i]; }
    psum += __shfl_xor(psum, 16);
    psum += __shfl_xor(psum, 32);
    lsum = lsum*corr + psum;

    // redistribute P to PV A-fragment layout: pa[e] = bf16(P[qi][8g+e])
    bf16x8 pa;
    #pragma unroll
    for (int r = 0; r < 4; r++) {
      unsigned w = (unsigned)f2bf(p[r]) | ((unsigned)f2bf(p[4+r]) << 16);
      unsigned v0 = (unsigned)__shfl((int)w, src0);
      unsigned v1 = (unsigned)__shfl((int)w, src0 + 16);
      pa[r]     = (short)(hiHalf ? (v0 >> 16) : (v0 & 0xffff));
      pa[4 + r] = (short)(hiHalf ? (v1 >> 16) : (v1 & 0xffff));
    }

    // rescale accumulator: acc row r of this lane is query 4g+r
    float cq0 = __shfl(corr, 4*g + 0);
    float cq1 = __shfl(corr, 4*g + 1);
    float cq2 = __shfl(corr, 4*g + 2);
    float cq3 = __shfl(corr, 4*g + 3);
    f32x4 cqv = (f32x4){cq0, cq1, cq2, cq3};
    #pragma unroll
    for (int d = 0; d < 4; d++) o[d] *= cqv;

    o[0] = __builtin_amdgcn_mfma_f32_16x16x32_bf16(pa, cv0, o[0], 0, 0, 0);
    o[1] = __builtin_amdgcn_mfma_f32_16x16x32_bf16(pa, cv1, o[1], 0, 0, 0);
    o[2] = __builtin_amdgcn_mfma_f32_16x16x32_bf16(pa, cv2, o[2], 0, 0, 0);
    o[3] = __builtin_amdgcn_mfma_f32_16x16x32_bf16(pa, cv3, o[3], 0, 0, 0);

    // rotate prefetched registers in
    cka0 = nka0; cka1 = nka1; ckb0 = nkb0; ckb1 = nkb1;
    cv0 = nv0; cv1 = nv1; cv2 = nv2; cv3 = nv3;
  }

  // epilogue: lane holds O[q0+4g+r][h*64 + d*16 + qi]
  float inv = 1.0f / lsum;
  float li0 = __shfl(inv, 4*g + 0);
  float li1 = __shfl(inv, 4*g + 1);
  float li2 = __shfl(inv, 4*g + 2);
  float li3 = __shfl(inv, 4*g + 3);
  f32x4 liv = (f32x4){li0, li1, li2, li3};
  #pragma unroll
  for (int r = 0; r < 4; r++) {
    int row = q0 + 4*g + r;
    if (row < T1N) {
      __hip_bfloat16* op = out + (size_t)row*DMODEL + h*64 + qi;
      #pragma unroll
      for (int d = 0; d < 4; d++) op[d*16] = __float2bfloat16(o[d][r] * liv[r]);
    }
  }
}

// ---------------- residual + LayerNorm: wave-per-row, no LDS, no barriers ----------------
__global__ __launch_bounds__(256) void ln_kernel(
    const __hip_bfloat16* __restrict__ xin, const __hip_bfloat16* __restrict__ yin,
    const float* __restrict__ g, const float* __restrict__ b,
    __hip_bfloat16* __restrict__ xbout, float* __restrict__ fout) {
  const int wid = threadIdx.x >> 6, lane = threadIdx.x & 63;
  const int row = blockIdx.x*4 + wid;
  if (row >= T1N) return;       // wave-uniform
  const size_t base = (size_t)row*DMODEL + lane*8;
  uint4 xw = *(const uint4*)(xin + base);
  uint4 yw = *(const uint4*)(yin + base);
  float v[8];
  float s = 0.0f, sq = 0.0f;
  #pragma unroll
  for (int j = 0; j < 4; j++) {
    unsigned xx = ((const unsigned*)&xw)[j], yy = ((const unsigned*)&yw)[j];
    float a0 = bf2f((unsigned short)(xx & 0xffff)) + bf2f((unsigned short)(yy & 0xffff));
    float a1 = bf2f((unsigned short)(xx >> 16))    + bf2f((unsigned short)(yy >> 16));
    v[2*j] = a0; v[2*j+1] = a1;
    s += a0 + a1; sq += a0*a0 + a1*a1;
  }
  #pragma unroll
  for (int off = 1; off < 64; off <<= 1) {
    s  += __shfl_xor(s, off);
    sq += __shfl_xor(sq, off);
  }
  float mean = s * (1.0f/512.0f);
  float var  = sq * (1.0f/512.0f) - mean*mean;
  float rstd = rsqrtf(var + 1e-5f);
  float4 g0 = *(const float4*)(g + lane*8), g1 = *(const float4*)(g + lane*8 + 4);
  float4 b0 = *(const float4*)(b + lane*8), b1 = *(const float4*)(b + lane*8 + 4);
  float gg[8] = {g0.x,g0.y,g0.z,g0.w,g1.x,g1.y,g1.z,g1.w};
  float bb[8] = {b0.x,b0.y,b0.z,b0.w,b1.x,b1.y,b1.z,b1.w};
  float o[8];
  #pragma unroll
  for (int j = 0; j < 8; j++) o[j] = (v[j] - mean)*rstd*gg[j] + bb[j];
  unsigned pk[4];
  #pragma unroll
  for (int j = 0; j < 4; j++)
    pk[j] = (unsigned)f2bf(o[2*j]) | ((unsigned)f2bf(o[2*j+1]) << 16);
  *(uint4*)(xbout + base) = *(uint4*)pk;
  if (fout) {
    *(float4*)(fout + base)     = make_float4(o[0], o[1], o[2], o[3]);
    *(float4*)(fout + base + 4) = make_float4(o[4], o[5], o[6], o[7]);
  }
}

extern "C" void kernel_launch(void* const* d_in, const int* in_sizes, int n_in,
                              void* d_out, int out_size, void* d_ws, size_t ws_size,
                              hipStream_t stream) {
  const int*   aseq   = (const int*)d_in[0];
  const int*   bid    = (const int*)d_in[1];
  const float* W_type = (const float*)d_in[2];
  const float* b_type = (const float*)d_in[3];
  const float* W_arg  = (const float*)d_in[4];
  const float* b_arg  = (const float*)d_in[5];
  const float* sosv   = (const float*)d_in[6];
  const float* Wq = (const float*)d_in[7];
  const float* bq = (const float*)d_in[8];
  const float* Wk = (const float*)d_in[9];
  const float* bk = (const float*)d_in[10];
  const float* Wv = (const float*)d_in[11];
  const float* bv = (const float*)d_in[12];
  const float* Wo = (const float*)d_in[13];
  const float* bo = (const float*)d_in[14];
  const float* ln1g = (const float*)d_in[15];
  const float* ln1b = (const float*)d_in[16];
  const float* W1 = (const float*)d_in[17];
  const float* b1 = (const float*)d_in[18];
  const float* W2 = (const float*)d_in[19];
  const float* b2 = (const float*)d_in[20];
  const float* ln2g = (const float*)d_in[21];
  const float* ln2b = (const float*)d_in[22];

  char* wsp = (char*)d_ws;
  size_t off = 0;
  auto alloc = [&](size_t bytes) -> void* {
    void* p = wsp + off; off += (bytes + 255) & ~(size_t)255; return p;
  };
  __hip_bfloat16* WT  = (__hip_bfloat16*)alloc((size_t)12*512*512*2);
  __hip_bfloat16* xb  = (__hip_bfloat16*)alloc((size_t)T1N*DMODEL*2);
  __hip_bfloat16* qb  = (__hip_bfloat16*)alloc((size_t)T1N*DMODEL*2);
  __hip_bfloat16* kbf = (__hip_bfloat16*)alloc((size_t)T1N*DMODEL*2);
  __hip_bfloat16* vtb = (__hip_bfloat16*)alloc((size_t)512*VTS*2);
  __hip_bfloat16* yb  = (__hip_bfloat16*)alloc((size_t)T1N*DMODEL*2);
  __hip_bfloat16* ab  = (__hip_bfloat16*)alloc((size_t)T1N*DMODEL*2);
  __hip_bfloat16* f1b = (__hip_bfloat16*)alloc((size_t)T1N*DMODEL*2);
  int* ss             = (int*)alloc((size_t)T_TOK*4);

  prep_kernel<<<dim3(EMB_BLKS + 12*256), 256, 0, stream>>>(
      aseq, bid, W_type, b_type, W_arg, b_arg, sosv,
      Wq, Wk, Wv, Wo, W1, W2, xb, ss, WT);

  const size_t WSZ = (size_t)512*512;
  const dim3 ggrid(65, 8);
  const dim3 qgrid(33, 12);
  for (int l = 0; l < 2; l++) {
    const __hip_bfloat16* Bq  = WT + (size_t)(0*2+l)*WSZ;
    const __hip_bfloat16* Bk  = WT + (size_t)(1*2+l)*WSZ;
    const __hip_bfloat16* Bv  = WT + (size_t)(2*2+l)*WSZ;
    const __hip_bfloat16* Bo  = WT + (size_t)(3*2+l)*WSZ;
    const __hip_bfloat16* Bf1 = WT + (size_t)(4*2+l)*WSZ;
    const __hip_bfloat16* Bf2 = WT + (size_t)(5*2+l)*WSZ;

    gemm_qkv<<<qgrid, 256, 0, stream>>>(xb, Bq, Bk, Bv,
        bq + l*512, bk + l*512, bv + l*512, qb, kbf, vtb, T1N);
    attn_kernel<<<dim3(257,8), 64, 0, stream>>>(qb, kbf, vtb, ss, ab);
    gemm_one<0><<<ggrid, 256, 0, stream>>>(ab, Bo, bo + l*512, yb, T1N);
    ln_kernel<<<dim3(1025), 256, 0, stream>>>(xb, yb, ln1g + l*512, ln1b + l*512, xb, nullptr);
    gemm_one<1><<<ggrid, 256, 0, stream>>>(xb, Bf1, b1 + l*512, f1b, T1N);
    gemm_one<0><<<ggrid, 256, 0, stream>>>(f1b, Bf2, b2 + l*512, yb, T1N);
    float* fout = (l == 1) ? (float*)d_out : nullptr;
    ln_kernel<<<dim3(1025), 256, 0, stream>>>(xb, yb, ln2g + l*512, ln2b + l*512, xb, fout);
  }
}